// Round 12
// baseline (1243.680 us; speedup 1.0000x reference)
//
#include <hip/hip_runtime.h>
#include <hip/hip_bf16.h>

typedef unsigned int u32;
typedef unsigned short u16;
typedef _Float16 f16;
typedef f16 f16x2 __attribute__((ext_vector_type(2)));

#define BB 128
#define TT 512
#define HE 256      // encoder hidden
#define G3E 768
#define HD 512      // decoder hidden (2H)
#define G3D 1536
#define LL 64
#define NDICT 30
#define EMBD 256

__device__ __forceinline__ float fexp2(float v){
#if __has_builtin(__builtin_amdgcn_exp2f)
  return __builtin_amdgcn_exp2f(v);
#else
  return exp2f(v);
#endif
}
__device__ __forceinline__ float frcp(float v){
#if __has_builtin(__builtin_amdgcn_rcpf)
  return __builtin_amdgcn_rcpf(v);
#else
  return 1.f/v;
#endif
}
__device__ __forceinline__ float sigm(float v){
  return frcp(1.f + fexp2(-1.4426950408889634f*v));
}
__device__ __forceinline__ float ftanh(float v){
  float e = fexp2(fminf(v, 40.f)*2.8853901631790583f);
  return (e - 1.f)*frcp(e + 1.f);
}
__device__ __forceinline__ u16 f2h(float f){ return __builtin_bit_cast(u16, (f16)f); }
__device__ __forceinline__ float h2f(u16 b){ return (float)__builtin_bit_cast(f16, b); }
__device__ __forceinline__ u32 pkh2(float a, float b){
  u16 lo = __builtin_bit_cast(u16, (f16)a);
  u16 hi = __builtin_bit_cast(u16, (f16)b);
  return (u32)lo | ((u32)hi << 16);
}
__device__ __forceinline__ u32 pkrtz(float a, float b){
  return __builtin_bit_cast(u32, __builtin_amdgcn_cvt_pkrtz(a, b));
}
__device__ __forceinline__ f16x2 bc2(u32 v){ return __builtin_bit_cast(f16x2, v); }

__device__ __forceinline__ void unp8h(uint4 v, float* d){
  f16x2 p;
  p = bc2(v.x); d[0]=(float)p.x; d[1]=(float)p.y;
  p = bc2(v.y); d[2]=(float)p.x; d[3]=(float)p.y;
  p = bc2(v.z); d[4]=(float)p.x; d[5]=(float)p.y;
  p = bc2(v.w); d[6]=(float)p.x; d[7]=(float)p.y;
}
__device__ __forceinline__ ushort4 hpk4(float a, float b, float c, float d){
  ushort4 r; r.x=f2h(a); r.y=f2h(b); r.z=f2h(c); r.w=f2h(d); return r;
}

// dot2: acc += a(2xf16) . b(2xf16), f32 accumulate — REAL v_dot2_f32_f16
__device__ __forceinline__ float dot2a(u32 a, u32 b, float c){
  float d;
  asm("v_dot2_f32_f16 %0, %1, %2, %3" : "=v"(d) : "v"(a), "v"(b), "v"(c));
  return d;
}
__device__ __forceinline__ float dot2h(u32 a, u32 b, float acc){
  return dot2a(a, b, acc);
}
__device__ __forceinline__ void dot_u4(uint4 wv, uint4 hv, float& acc){
  acc = dot2a(wv.x, hv.x, acc);
  acc = dot2a(wv.y, hv.y, acc);
  acc = dot2a(wv.z, hv.z, acc);
  acc = dot2a(wv.w, hv.w, acc);
}

// f16-pair dot2 inner (A2_s/B2_s u32[16][68], each u32 = 2 consecutive k)
#define INNER8P(Q0,Q1)                                                  \
  _Pragma("unroll")                                                     \
  for (int kp = 0; kp < 16; ++kp){                                      \
    uint4 a2 = *(const uint4*)&A2_s[kp*68 + (Q0)*4];                    \
    uint4 b2 = *(const uint4*)&B2_s[kp*68 + (Q1)*4];                    \
    acc[0] =dot2h(a2.x,b2.x,acc[0]);  acc[1] =dot2h(a2.x,b2.y,acc[1]);  \
    acc[2] =dot2h(a2.x,b2.z,acc[2]);  acc[3] =dot2h(a2.x,b2.w,acc[3]);  \
    acc[4] =dot2h(a2.y,b2.x,acc[4]);  acc[5] =dot2h(a2.y,b2.y,acc[5]);  \
    acc[6] =dot2h(a2.y,b2.z,acc[6]);  acc[7] =dot2h(a2.y,b2.w,acc[7]);  \
    acc[8] =dot2h(a2.z,b2.x,acc[8]);  acc[9] =dot2h(a2.z,b2.y,acc[9]);  \
    acc[10]=dot2h(a2.z,b2.z,acc[10]); acc[11]=dot2h(a2.z,b2.w,acc[11]); \
    acc[12]=dot2h(a2.w,b2.x,acc[12]); acc[13]=dot2h(a2.w,b2.y,acc[13]); \
    acc[14]=dot2h(a2.w,b2.z,acc[14]); acc[15]=dot2h(a2.w,b2.w,acc[15]); \
  }

// ---------- prep: pair-transposed f16 weights ----------
__global__ __launch_bounds__(256) void k_prep_pairT(const float* __restrict__ src,
                                                    u32* __restrict__ dst, int N, int K){
  int idx = blockIdx.x*256 + threadIdx.x;
  int KP = K >> 1;
  if (idx < N*KP){
    int n = idx / KP, kp = idx - n*KP;
    dst[(size_t)kp*N + n] = pkh2(src[(size_t)n*K + 2*kp], src[(size_t)n*K + 2*kp + 1]);
  }
}

// ---------- prep: encoder Whh -> f16 tile layout [dir][i 32][t 768] uint4 ----------
__global__ __launch_bounds__(256) void k_prep_wenc(const float* __restrict__ WF,
                                                   const float* __restrict__ WB,
                                                   uint4* __restrict__ dst){
  int idx = blockIdx.x*256 + threadIdx.x;   // 49152 = 2*32*768
  int dir = idx / 24576, rem = idx - dir*24576;
  int i = rem / 768, t = rem - i*768;
  int rg = t >> 3, cg = t & 7;
  int r = i >> 2, q = i & 3;
  const float* s = (dir ? WB : WF) + (size_t)(rg*8 + r)*HE + cg*32 + q*8;
  uint4 v; v.x=pkh2(s[0],s[1]); v.y=pkh2(s[2],s[3]); v.z=pkh2(s[4],s[5]); v.w=pkh2(s[6],s[7]);
  dst[idx] = v;
}

// ---------- prep: decoder Whh -> f16 M-parallel layout ----------
__global__ __launch_bounds__(256) void k_prep_wdec(const float* __restrict__ src,
                                                   uint4* __restrict__ dst){
  int idx = blockIdx.x*256 + threadIdx.x;   // 98304 = 64*24*64
  int lane = idx & 63;
  int ci = lane & 7, kq = lane >> 3;
  int rest = idx >> 6;                      // cg*24 + g*8 + u
  int u = rest & 7, g = (rest >> 3) % 3, cg = rest / 24;
  int row = g*512 + cg*8 + ci;
  int col = kq*64 + u*8;
  const float* s = src + (size_t)row*HD + col;
  uint4 v; v.x=pkh2(s[0],s[1]); v.y=pkh2(s[2],s[3]); v.z=pkh2(s[4],s[5]); v.w=pkh2(s[6],s[7]);
  dst[idx] = v;
}

// ---------- prep: gi[v][g] = emb[v]@dWih[g] + bih[g] ----------
__global__ __launch_bounds__(256) void k_gi_tab(const float* __restrict__ emb,
                                                const float* __restrict__ Wih,
                                                const float* __restrict__ bih,
                                                float* __restrict__ gi){
  int v = blockIdx.x, gy = blockIdx.y;   // grid (30, 6)
  int g = gy*256 + threadIdx.x;
  __shared__ float e_s[EMBD];
  if (threadIdx.x < EMBD) e_s[threadIdx.x] = emb[(size_t)v*EMBD + threadIdx.x];
  __syncthreads();
  const float4* w4 = (const float4*)(Wih + (size_t)g*EMBD);
  float acc = 0.f;
  #pragma unroll 8
  for (int k = 0; k < EMBD/4; ++k){
    float4 w = w4[k];
    float4 h = *(const float4*)&e_s[k*4];
    acc = fmaf(w.x,h.x,fmaf(w.y,h.y,fmaf(w.z,h.z,fmaf(w.w,h.w,acc))));
  }
  gi[(size_t)v*G3D + g] = acc + bih[g];
}

// ---------- prep: h0 f32 -> f16 ----------
__global__ __launch_bounds__(256) void k_h0cvt(const float* __restrict__ src,
                                               f16* __restrict__ dst){
  int i = blockIdx.x*256 + threadIdx.x;   // 65536
  dst[i] = (f16)src[i];
}

// ---------- encoder: one block per (batch, direction) ----------
__global__ __launch_bounds__(768, 3) void k_enc_p(
    const float* __restrict__ x,
    const uint4* __restrict__ Wp,               // [2][32][768] uint4 tile layout
    const float* __restrict__ WihF, const float* __restrict__ WihB,
    const float* __restrict__ bihF, const float* __restrict__ bhhF,
    const float* __restrict__ bihB, const float* __restrict__ bhhB,
    u16* __restrict__ enc_out, float* __restrict__ h0out)
{
  const int b   = blockIdx.x >> 1;
  const int dir = blockIdx.x & 1;
  const int j   = threadIdx.x;
  const int cg  = j & 7;
  const float* Wih = dir ? WihB : WihF;
  const float* bih = dir ? bihB : bihF;
  const float* bhh = dir ? bhhB : bhhF;

  __shared__ __align__(16) f16 h_pad[8*40];  // 640 B, groups on distinct banks
  __shared__ float gh[2*HE];                 // finished r,z pre-acts
  __shared__ float gin_s[HE], ghn_s[HE];     // n-gate halves

  // weight tile -> 32 uint4 (128 VGPRs), coalesced
  uint4 w[32];
  {
    const uint4* wsrc = Wp + (size_t)dir*24576 + j;
    #pragma unroll
    for (int i = 0; i < 32; ++i) w[i] = wsrc[(size_t)i*768];
  }
  const float wv0r = Wih[j*2+0], wv1r = Wih[j*2+1];
  const float bi = bih[j], bh = bhh[j];
  const float badd = bi + bh;               // for r,z rows
  if (j < HE) h_pad[(j >> 5)*40 + (j & 31)] = (f16)0.f;
  float h_own = 0.f;
  const bool s0 = (cg & 1), s1 = (cg & 2), s2 = (cg & 4);
  __syncthreads();

  for (int t = 0; t < TT; ++t){
    const int tt = dir ? (TT-1-t) : t;
    const float x0 = x[((size_t)b*TT + tt)*2 + 0];
    const float x1 = x[((size_t)b*TT + tt)*2 + 1];

    // 4 b128 h reads (this thread's 32-col slice), 8 independent row-dots
    const uint4* hv = (const uint4*)(h_pad + cg*40);
    uint4 h0 = hv[0], h1 = hv[1], h2 = hv[2], h3 = hv[3];
    float p[8];
    #pragma unroll
    for (int r = 0; r < 8; ++r){
      float a = 0.f;
      dot_u4(w[r*4+0], h0, a);
      dot_u4(w[r*4+1], h1, a);
      dot_u4(w[r*4+2], h2, a);
      dot_u4(w[r*4+3], h3, a);
      p[r] = a;
    }
    // 8-lane transpose-reduce: lane cg ends with full sum for row rg*8+cg
    float q0 = (s0 ? p[1] : p[0]) + __shfl_xor(s0 ? p[0] : p[1], 1);
    float q1 = (s0 ? p[3] : p[2]) + __shfl_xor(s0 ? p[2] : p[3], 1);
    float q2 = (s0 ? p[5] : p[4]) + __shfl_xor(s0 ? p[4] : p[5], 1);
    float q3 = (s0 ? p[7] : p[6]) + __shfl_xor(s0 ? p[6] : p[7], 1);
    float r0 = (s1 ? q1 : q0) + __shfl_xor(s1 ? q0 : q1, 2);
    float r1 = (s1 ? q3 : q2) + __shfl_xor(s1 ? q2 : q3, 2);
    float tot = (s2 ? r1 : r0) + __shfl_xor(s2 ? r0 : r1, 4);

    const float xp = fmaf(wv0r, x0, wv1r*x1);
    if (j < 2*HE){
      gh[j] = tot + xp + badd;              // r,z: fully folded
    } else {
      ghn_s[j-2*HE] = tot + bh;
      gin_s[j-2*HE] = xp + bi;
    }
    __syncthreads();
    if (j < HE){
      float r = sigm(gh[j]);
      float z = sigm(gh[j+HE]);
      float n = ftanh(gin_s[j] + r*ghn_s[j]);
      float hnew = (1.f - z)*n + z*h_own;
      h_own = hnew;
      h_pad[(j >> 5)*40 + (j & 31)] = (f16)hnew;
      enc_out[((size_t)b*TT + tt)*HD + dir*HE + j] = f2h(hnew);
    }
    __syncthreads();
  }
  if (j < HE) h0out[(size_t)b*HD + dir*HE + j] = h_own;
}

// ---------- decoder: ONE STEP per launch, M-parallel ----------
__global__ __launch_bounds__(256, 2) void k_dstep(
    const int* __restrict__ tgt, const float* __restrict__ gi_tab,
    const uint4* __restrict__ Wd2, const float* __restrict__ bhh,
    const f16* __restrict__ h_prev, f16* __restrict__ h_next,
    float* __restrict__ Hall, int l)
{
  const int bg = blockIdx.x & 7, cg = blockIdx.x >> 3;
  const int tid = threadIdx.x;
  const int ci = tid & 7, kq = (tid >> 3) & 7, bq = tid >> 6;

  __shared__ __align__(16) f16 h_s[16][8][72];    // 18.4 KB, padded segments
  __shared__ float p_s[3][16][8][9];              // 13.8 KB [g][b][ci][kq+pad]
  __shared__ int tok_s[16];

  uint4 w[24];
  {
    const uint4* wp = Wd2 + (size_t)cg*24*64 + (kq*8 + ci);
    #pragma unroll
    for (int i = 0; i < 24; ++i) w[i] = wp[(size_t)i*64];
  }
  {
    const uint4* hsrc = (const uint4*)(h_prev + (size_t)bg*16*HD);
    #pragma unroll
    for (int i = 0; i < 4; ++i){
      int idx = tid + i*256;
      int b = idx >> 6, w4 = idx & 63;
      int kq2 = w4 >> 3, off = w4 & 7;
      *(uint4*)&h_s[b][kq2][off*8] = hsrc[idx];
    }
  }
  if (tid < 16) tok_s[tid] = (l == 0) ? 1 : tgt[(size_t)(bg*16 + tid)*LL + l - 1];
  __syncthreads();

  #pragma unroll
  for (int nb = 0; nb < 4; ++nb){
    const int b = bq*4 + nb;
    const uint4* hv = (const uint4*)&h_s[b][kq][0];
    float x0 = 0.f, x1 = 0.f, x2 = 0.f;
    #pragma unroll
    for (int u = 0; u < 8; ++u){
      uint4 hh = hv[u];
      dot_u4(w[u],      hh, x0);
      dot_u4(w[8 + u],  hh, x1);
      dot_u4(w[16 + u], hh, x2);
    }
    p_s[0][b][ci][kq] = x0;
    p_s[1][b][ci][kq] = x1;
    p_s[2][b][ci][kq] = x2;
  }
  __syncthreads();

  if (tid < 128){
    const int b = tid >> 3, cl = tid & 7;
    const int C = cg*8 + cl;
    float s0 = 0.f, s1 = 0.f, s2 = 0.f;
    #pragma unroll
    for (int k = 0; k < 8; ++k){
      s0 += p_s[0][b][cl][k];
      s1 += p_s[1][b][cl][k];
      s2 += p_s[2][b][cl][k];
    }
    const int tok = tok_s[b];
    const float* gp = gi_tab + (size_t)tok*G3D + C;
    float r = sigm(gp[0]    + s0 + bhh[C]);
    float z = sigm(gp[HD]   + s1 + bhh[HD + C]);
    float n = ftanh(gp[2*HD] + r*(s2 + bhh[2*HD + C]));
    float hp = (float)h_s[b][C >> 6][C & 63];
    float hnew = (1.f - z)*n + z*hp;
    const int gb = bg*16 + b;
    h_next[(size_t)gb*HD + C] = (f16)hnew;
    Hall[((size_t)l*BB + gb)*HD + C] = hnew;
  }
}

// ---------- Q = Hall @ WqT + bq -> f16 ; grid (128 rt, 8 nt), dot2 inner ----------
__global__ __launch_bounds__(256) void k_query(const float* __restrict__ Hall,
                                               const u32* __restrict__ Wq2,
                                               const float* __restrict__ bq,
                                               u16* __restrict__ Qh){
  const int rt = blockIdx.x, nt = blockIdx.y;
  const int tid = threadIdx.x;
  __shared__ u32 A2_s[16*68];
  __shared__ u32 B2_s[16*68];
  const int rq = tid >> 4, nq = tid & 15;
  const int i = tid >> 2, jj = tid & 3;
  const int i3 = tid >> 4, n4 = tid & 15;
  float acc[16] = {};
  for (int kc = 0; kc < 16; ++kc){
    __syncthreads();
    {
      const float* src = Hall + (size_t)(rt*64 + i)*HD + kc*32 + jj*8;
      float4 v0 = *(const float4*)src, v1 = *(const float4*)(src+4);
      A2_s[(jj*4+0)*68+i] = pkrtz(v0.x, v0.y);
      A2_s[(jj*4+1)*68+i] = pkrtz(v0.z, v0.w);
      A2_s[(jj*4+2)*68+i] = pkrtz(v1.x, v1.y);
      A2_s[(jj*4+3)*68+i] = pkrtz(v1.z, v1.w);
    }
    {
      uint4 v = *(const uint4*)(Wq2 + (size_t)(kc*16 + i3)*HD + nt*64 + n4*4);
      *(uint4*)&B2_s[i3*68 + n4*4] = v;
    }
    __syncthreads();
    INNER8P(rq, nq)
  }
  const int n0 = nt*64 + nq*4;
  float4 bv = *(const float4*)&bq[n0];
  #pragma unroll
  for (int r = 0; r < 4; ++r){
    u16* dst = Qh + (size_t)(rt*64 + rq*4 + r)*HD + n0;
    *(ushort4*)dst = hpk4(acc[r*4+0]+bv.x, acc[r*4+1]+bv.y,
                          acc[r*4+2]+bv.z, acc[r*4+3]+bv.w);
  }
}

// ---------- S[b][l][t] = Q[b,l,:] . enc[b,t,:] ; grid (128 b, 8 tt), dot2 ----------
__global__ __launch_bounds__(256) void k_scores(const u16* __restrict__ Qh,
                                                const u16* __restrict__ enc,
                                                float* __restrict__ Sbuf){
  const int bI = blockIdx.x, tt = blockIdx.y;
  const int tid = threadIdx.x;
  __shared__ u32 A2_s[16*68];
  __shared__ u32 B2_s[16*68];
  const int lq = tid >> 4, tq = tid & 15;
  const int i = tid >> 2, jj = tid & 3;
  float acc[16] = {};
  for (int kc = 0; kc < 16; ++kc){
    __syncthreads();
    {
      uint4 va = *(const uint4*)(Qh + ((size_t)i*BB + bI)*HD + kc*32 + jj*8);
      A2_s[(jj*4+0)*68+i] = va.x;
      A2_s[(jj*4+1)*68+i] = va.y;
      A2_s[(jj*4+2)*68+i] = va.z;
      A2_s[(jj*4+3)*68+i] = va.w;
    }
    {
      uint4 vb = *(const uint4*)(enc + ((size_t)bI*TT + tt*64 + i)*HD + kc*32 + jj*8);
      B2_s[(jj*4+0)*68+i] = vb.x;
      B2_s[(jj*4+1)*68+i] = vb.y;
      B2_s[(jj*4+2)*68+i] = vb.z;
      B2_s[(jj*4+3)*68+i] = vb.w;
    }
    __syncthreads();
    INNER8P(lq, tq)
  }
  #pragma unroll
  for (int r = 0; r < 4; ++r){
    float4 o = make_float4(acc[r*4+0],acc[r*4+1],acc[r*4+2],acc[r*4+3]);
    *(float4*)&Sbuf[((size_t)bI*LL + lq*4+r)*TT + tt*64 + tq*4] = o;
  }
}

// ---------- row softmax over t: P f16 ; grid 8192 x 64 ----------
__global__ __launch_bounds__(64) void k_softmax(const float* __restrict__ Sbuf,
                                                u16* __restrict__ Ph){
  const int row = blockIdx.x;
  const int lane = threadIdx.x;
  const float* s = Sbuf + (size_t)row*TT;
  float v[8]; float m = -1e30f;
  #pragma unroll
  for (int i = 0; i < 8; ++i){ v[i] = s[lane + i*64]; m = fmaxf(m, v[i]); }
  #pragma unroll
  for (int o = 32; o; o >>= 1) m = fmaxf(m, __shfl_xor(m, o));
  float Z = 0.f;
  #pragma unroll
  for (int i = 0; i < 8; ++i){ v[i] = fexp2(1.4426950408889634f*(v[i] - m)); Z += v[i]; }
  #pragma unroll
  for (int o = 32; o; o >>= 1) Z += __shfl_xor(Z, o);
  float inv = frcp(Z);
  u16* p = Ph + (size_t)row*TT;
  #pragma unroll
  for (int i = 0; i < 8; ++i) p[lane + i*64] = f2h(v[i]*inv);
}

// ---------- attn[b][t][l] = f32(P[b][l][t]) ; grid (128 b, 8 tt) ----------
__global__ __launch_bounds__(256) void k_attn_tr(const u16* __restrict__ Ph,
                                                 float* __restrict__ att){
  const int bI = blockIdx.x, tt = blockIdx.y;
  const int tid = threadIdx.x;
  __shared__ u16 tile[64][72];
  {
    const int i = tid >> 2, jj = tid & 3;
    #pragma unroll
    for (int rep = 0; rep < 2; ++rep){
      int ch = jj + rep*4;
      uint4 v = *(const uint4*)(Ph + ((size_t)bI*LL + i)*TT + tt*64 + ch*8);
      *(uint4*)&tile[i][ch*8] = v;
    }
  }
  __syncthreads();
  const int t = tid >> 2, jl = tid & 3;
  #pragma unroll
  for (int rep = 0; rep < 4; ++rep){
    int l0 = jl*16 + rep*4;
    float4 o;
    o.x = h2f(tile[l0+0][t]); o.y = h2f(tile[l0+1][t]);
    o.z = h2f(tile[l0+2][t]); o.w = h2f(tile[l0+3][t]);
    *(float4*)&att[((size_t)bI*TT + tt*64 + t)*LL + l0] = o;
  }
}

// ---------- ctx[l*128+b][n] = P[b,l,:] @ enc[b,:,n] -> f16 ; dot2 inner ----------
// A (P) pairs are t-contiguous: direct pair loads. B (enc) pairs span t-rows:
// interleave two rows at LDS-write time (4 bit-packs/thread).
__global__ __launch_bounds__(256) void k_ctx(const u16* __restrict__ Ph,
                                             const u16* __restrict__ enc,
                                             u16* __restrict__ ctxh){
  const int bI = blockIdx.x, nt = blockIdx.y;
  const int tid = threadIdx.x;
  __shared__ u32 A2_s[16*68];
  __shared__ u32 B2_s[16*68];
  const int lq = tid >> 4, nq = tid & 15;
  const int i = tid >> 2, jj = tid & 3;
  const int q = tid >> 4, n4 = tid & 15;
  float acc[16] = {};
  for (int tc = 0; tc < 16; ++tc){
    __syncthreads();
    {
      uint4 va = *(const uint4*)(Ph + ((size_t)bI*LL + i)*TT + tc*32 + jj*8);
      A2_s[(jj*4+0)*68+i] = va.x;
      A2_s[(jj*4+1)*68+i] = va.y;
      A2_s[(jj*4+2)*68+i] = va.z;
      A2_s[(jj*4+3)*68+i] = va.w;
    }
    {
      const int t0 = tc*32 + 2*q;
      const int n0 = nt*64 + n4*4;
      uint2 a = *(const uint2*)(enc + ((size_t)bI*TT + t0)*HD + n0);
      uint2 b = *(const uint2*)(enc + ((size_t)bI*TT + t0 + 1)*HD + n0);
      B2_s[q*68 + n4*4 + 0] = (a.x & 0xffffu) | (b.x << 16);
      B2_s[q*68 + n4*4 + 1] = (a.x >> 16) | (b.x & 0xffff0000u);
      B2_s[q*68 + n4*4 + 2] = (a.y & 0xffffu) | (b.y << 16);
      B2_s[q*68 + n4*4 + 3] = (a.y >> 16) | (b.y & 0xffff0000u);
    }
    __syncthreads();
    INNER8P(lq, nq)
  }
  const int n0 = nt*64 + nq*4;
  #pragma unroll
  for (int r = 0; r < 4; ++r){
    int ll = lq*4 + r;
    u16* dst = ctxh + ((size_t)ll*BB + bI)*HD + n0;
    *(ushort4*)dst = hpk4(acc[r*4+0], acc[r*4+1], acc[r*4+2], acc[r*4+3]);
  }
}

// ---------- o = [Hall|ctx] @ WcT + bc ; grid (128 rt, 4 nt), dot2 ----------
__global__ __launch_bounds__(256) void k_outc(const float* __restrict__ Hall,
                                              const u16* __restrict__ ctxh,
                                              const u32* __restrict__ Wc2,
                                              const float* __restrict__ bc,
                                              float* __restrict__ obuf){
  const int rt = blockIdx.x, nt = blockIdx.y;
  const int tid = threadIdx.x;
  __shared__ u32 A2_s[16*68];
  __shared__ u32 B2_s[16*68];
  const int rq = tid >> 4, nq = tid & 15;
  const int i = tid >> 2, jj = tid & 3;
  const int i3 = tid >> 4, n4 = tid & 15;
  float acc[16] = {};
  for (int kc = 0; kc < 32; ++kc){
    __syncthreads();
    if (kc < 16){
      const float* src = Hall + (size_t)(rt*64 + i)*HD + kc*32 + jj*8;
      float4 v0 = *(const float4*)src, v1 = *(const float4*)(src+4);
      A2_s[(jj*4+0)*68+i] = pkrtz(v0.x, v0.y);
      A2_s[(jj*4+1)*68+i] = pkrtz(v0.z, v0.w);
      A2_s[(jj*4+2)*68+i] = pkrtz(v1.x, v1.y);
      A2_s[(jj*4+3)*68+i] = pkrtz(v1.z, v1.w);
    } else {
      uint4 v = *(const uint4*)(ctxh + (size_t)(rt*64 + i)*HD + (kc-16)*32 + jj*8);
      A2_s[(jj*4+0)*68+i] = v.x;
      A2_s[(jj*4+1)*68+i] = v.y;
      A2_s[(jj*4+2)*68+i] = v.z;
      A2_s[(jj*4+3)*68+i] = v.w;
    }
    {
      uint4 v = *(const uint4*)(Wc2 + (size_t)(kc*16 + i3)*256 + nt*64 + n4*4);
      *(uint4*)&B2_s[i3*68 + n4*4] = v;
    }
    __syncthreads();
    INNER8P(rq, nq)
  }
  const int n0 = nt*64 + nq*4;
  float4 bv = *(const float4*)&bc[n0];
  #pragma unroll
  for (int r = 0; r < 4; ++r){
    float4 o = make_float4(acc[r*4+0]+bv.x, acc[r*4+1]+bv.y,
                           acc[r*4+2]+bv.z, acc[r*4+3]+bv.w);
    *(float4*)&obuf[(size_t)(rt*64 + rq*4 + r)*256 + n0] = o;
  }
}

// ---------- logits = o @ Wf^T + bf ; grid 128 ----------
__global__ __launch_bounds__(256) void k_fc(const float* __restrict__ obuf,
                                            const float* __restrict__ Wf,
                                            const float* __restrict__ bfv,
                                            float* __restrict__ out_vec){
  const int rt = blockIdx.x;
  const int tid = threadIdx.x;
  __shared__ float w_s[30*260];
  for (int rr = 0; rr < 30; ++rr) w_s[rr*260 + tid] = Wf[(size_t)rr*256 + tid];
  __syncthreads();
  const int rl = tid >> 2, dq = tid & 3;
  const int r = rt*64 + rl;
  float acc[8] = {};
  for (int k = 0; k < 256; k += 4){
    float4 o4 = *(const float4*)&obuf[(size_t)r*256 + k];
    #pragma unroll
    for (int jq = 0; jq < 8; ++jq){
      int d = dq*8 + jq;
      if (d < 30){
        float4 w4 = *(const float4*)&w_s[d*260 + k];
        acc[jq] = fmaf(o4.x,w4.x,fmaf(o4.y,w4.y,fmaf(o4.z,w4.z,fmaf(o4.w,w4.w,acc[jq]))));
      }
    }
  }
  const int b = r & 127, l = r >> 7;
  #pragma unroll
  for (int jq = 0; jq < 8; ++jq){
    int d = dq*8 + jq;
    if (d < 30) out_vec[((size_t)b*LL + l)*NDICT + d] = acc[jq] + bfv[d];
  }
}

__global__ __launch_bounds__(256) void k_copy(const float* __restrict__ src,
                                              float* __restrict__ dst, int n){
  int i = blockIdx.x*256 + threadIdx.x;
  if (i < n) dst[i] = src[i];
}

extern "C" void kernel_launch(void* const* d_in, const int* in_sizes, int n_in,
                              void* d_out, int out_size, void* d_ws, size_t ws_size,
                              hipStream_t stream)
{
  const float* x     = (const float*)d_in[0];
  const int*   tgt   = (const int*)  d_in[1];
  const float* eWihF = (const float*)d_in[2];
  const float* eWhhF = (const float*)d_in[3];
  const float* ebihF = (const float*)d_in[4];
  const float* ebhhF = (const float*)d_in[5];
  const float* eWihB = (const float*)d_in[6];
  const float* eWhhB = (const float*)d_in[7];
  const float* ebihB = (const float*)d_in[8];
  const float* ebhhB = (const float*)d_in[9];
  const float* emb   = (const float*)d_in[10];
  const float* dWih  = (const float*)d_in[11];
  const float* dWhh  = (const float*)d_in[12];
  const float* dbih  = (const float*)d_in[13];
  const float* dbhh  = (const float*)d_in[14];
  const float* Wq    = (const float*)d_in[15];
  const float* bq    = (const float*)d_in[16];
  const float* Wc    = (const float*)d_in[17];
  const float* bc    = (const float*)d_in[18];
  const float* Wf    = (const float*)d_in[19];
  const float* bfv   = (const float*)d_in[20];

  char* w = (char*)d_ws;
  uint4* Wpenc = (uint4*)w; w += 786432;     // [2][32][768] uint4 f16 tile layout
  uint4* Wpdec = (uint4*)w; w += 1572864;    // [64][24][64] uint4 f16 M-parallel
  u32*   Wq2   = (u32*)w;  w += 524288;      // [256 kp][512 n] f16 pairs
  u32*   Wc2   = (u32*)w;  w += 524288;      // [512 kp][256 n] f16 pairs
  float* gi_t  = (float*)w; w += 184320;
  float* h0buf = (float*)w; w += 262144;
  f16*   h16A  = (f16*)w; w += 131072;       // [128][512] f16
  f16*   h16B  = (f16*)w; w += 131072;
  float* Hall  = (float*)w; w += 16777216;
  u16*   Qh    = (u16*)w;                    // aliased: Ph reuses after k_scores
  u16*   Ph    = (u16*)w; w += 8388608;
  float* Sbuf  = (float*)w;                  // aliased over (ctxh | obuf)
  u16*   ctxh  = (u16*)w; w += 8388608;
  float* obuf  = (float*)w; w += 8388608;
  u16*   ench  = (u16*)w; w += 67108864;

  float* out     = (float*)d_out;
  float* out_vec = out;                              // [128][64][30]
  float* out_hT  = out + (size_t)BB*LL*NDICT;        // [1][128][512]
  float* out_att = out_hT + (size_t)BB*HD;           // [128][512][64]

  // prep
  k_prep_wenc<<<192, 256, 0, stream>>>(eWhhF, eWhhB, Wpenc);
  k_prep_wdec<<<384, 256, 0, stream>>>(dWhh, Wpdec);
  k_prep_pairT<<<512, 256, 0, stream>>>(Wq, Wq2, HD, HD);
  k_prep_pairT<<<512, 256, 0, stream>>>(Wc, Wc2, 256, 1024);
  k_gi_tab<<<dim3(NDICT, 6), 256, 0, stream>>>(emb, dWih, dbih, gi_t);

  // encoder: 256 independent recurrences, col-split dot + shfl butterfly
  k_enc_p<<<BB*2, G3E, 0, stream>>>(x, Wpenc, eWihF, eWihB,
                                    ebihF, ebhhF, ebihB, ebhhB, ench, h0buf);

  // decoder recurrence: one launch per step, M-parallel, conflict-free LDS
  k_h0cvt<<<256, 256, 0, stream>>>(h0buf, h16A);
  for (int l = 0; l < LL; ++l){
    const f16* hp = (l & 1) ? h16B : h16A;
    f16*       hn = (l & 1) ? h16A : h16B;
    k_dstep<<<512, 256, 0, stream>>>(tgt, gi_t, Wpdec, dbhh, hp, hn, Hall, l);
  }

  // batched post-recurrence pipeline
  k_query<<<dim3(128,8), 256, 0, stream>>>(Hall, Wq2, bq, Qh);
  k_scores<<<dim3(128,8), 256, 0, stream>>>(Qh, ench, Sbuf);
  k_softmax<<<BB*LL, 64, 0, stream>>>(Sbuf, Ph);
  k_attn_tr<<<dim3(128,8), 256, 0, stream>>>(Ph, out_att);
  k_ctx<<<dim3(128,8), 256, 0, stream>>>(Ph, ench, ctxh);
  k_outc<<<dim3(128,4), 256, 0, stream>>>(Hall, ctxh, Wc2, bc, obuf);
  k_fc<<<BB, 256, 0, stream>>>(obuf, Wf, bfv, out_vec);
  k_copy<<<(BB*HD+255)/256, 256, 0, stream>>>(Hall + (size_t)63*BB*HD, out_hT, BB*HD);
}

// Round 13
// 1162.356 us; speedup vs baseline: 1.0700x; 1.0700x over previous
//
#include <hip/hip_runtime.h>
#include <hip/hip_bf16.h>

typedef unsigned int u32;
typedef unsigned short u16;
typedef _Float16 f16;
typedef f16 f16x2 __attribute__((ext_vector_type(2)));

#define BB 128
#define TT 512
#define HE 256      // encoder hidden
#define G3E 768
#define HD 512      // decoder hidden (2H)
#define G3D 1536
#define LL 64
#define NDICT 30
#define EMBD 256

__device__ __forceinline__ float fexp2(float v){
#if __has_builtin(__builtin_amdgcn_exp2f)
  return __builtin_amdgcn_exp2f(v);
#else
  return exp2f(v);
#endif
}
__device__ __forceinline__ float frcp(float v){
#if __has_builtin(__builtin_amdgcn_rcpf)
  return __builtin_amdgcn_rcpf(v);
#else
  return 1.f/v;
#endif
}
__device__ __forceinline__ float sigm(float v){
  return frcp(1.f + fexp2(-1.4426950408889634f*v));
}
__device__ __forceinline__ float ftanh(float v){
  float e = fexp2(fminf(v, 40.f)*2.8853901631790583f);
  return (e - 1.f)*frcp(e + 1.f);
}
__device__ __forceinline__ u16 f2h(float f){ return __builtin_bit_cast(u16, (f16)f); }
__device__ __forceinline__ float h2f(u16 b){ return (float)__builtin_bit_cast(f16, b); }
__device__ __forceinline__ u32 pkh2(float a, float b){
  u16 lo = __builtin_bit_cast(u16, (f16)a);
  u16 hi = __builtin_bit_cast(u16, (f16)b);
  return (u32)lo | ((u32)hi << 16);
}
__device__ __forceinline__ u32 pkrtz(float a, float b){
  return __builtin_bit_cast(u32, __builtin_amdgcn_cvt_pkrtz(a, b));
}
__device__ __forceinline__ f16x2 bc2(u32 v){ return __builtin_bit_cast(f16x2, v); }

__device__ __forceinline__ ushort4 hpk4(float a, float b, float c, float d){
  ushort4 r; r.x=f2h(a); r.y=f2h(b); r.z=f2h(c); r.w=f2h(d); return r;
}

// dot2: acc += a(2xf16) . b(2xf16), f32 accumulate — builtin (round-12 asm regressed)
__device__ __forceinline__ float dot2h(u32 a, u32 b, float acc){
#if __has_builtin(__builtin_amdgcn_fdot2)
  return __builtin_amdgcn_fdot2(bc2(a), bc2(b), acc, false);
#else
  float d;
  asm("v_dot2_f32_f16 %0, %1, %2, %3" : "=v"(d) : "v"(a), "v"(b), "v"(acc));
  return d;
#endif
}
__device__ __forceinline__ void dot_u4(uint4 wv, uint4 hv, float& acc){
  acc = dot2h(wv.x, hv.x, acc);
  acc = dot2h(wv.y, hv.y, acc);
  acc = dot2h(wv.z, hv.z, acc);
  acc = dot2h(wv.w, hv.w, acc);
}

// f16-pair dot2 inner (A2_s/B2_s u32[16][68], each u32 = 2 consecutive k)
#define INNER8P(Q0,Q1)                                                  \
  _Pragma("unroll")                                                     \
  for (int kp = 0; kp < 16; ++kp){                                      \
    uint4 a2 = *(const uint4*)&A2_s[kp*68 + (Q0)*4];                    \
    uint4 b2 = *(const uint4*)&B2_s[kp*68 + (Q1)*4];                    \
    acc[0] =dot2h(a2.x,b2.x,acc[0]);  acc[1] =dot2h(a2.x,b2.y,acc[1]);  \
    acc[2] =dot2h(a2.x,b2.z,acc[2]);  acc[3] =dot2h(a2.x,b2.w,acc[3]);  \
    acc[4] =dot2h(a2.y,b2.x,acc[4]);  acc[5] =dot2h(a2.y,b2.y,acc[5]);  \
    acc[6] =dot2h(a2.y,b2.z,acc[6]);  acc[7] =dot2h(a2.y,b2.w,acc[7]);  \
    acc[8] =dot2h(a2.z,b2.x,acc[8]);  acc[9] =dot2h(a2.z,b2.y,acc[9]);  \
    acc[10]=dot2h(a2.z,b2.z,acc[10]); acc[11]=dot2h(a2.z,b2.w,acc[11]); \
    acc[12]=dot2h(a2.w,b2.x,acc[12]); acc[13]=dot2h(a2.w,b2.y,acc[13]); \
    acc[14]=dot2h(a2.w,b2.z,acc[14]); acc[15]=dot2h(a2.w,b2.w,acc[15]); \
  }

// ---------- prep: pair-transposed f16 weights ----------
__global__ __launch_bounds__(256) void k_prep_pairT(const float* __restrict__ src,
                                                    u32* __restrict__ dst, int N, int K){
  int idx = blockIdx.x*256 + threadIdx.x;
  int KP = K >> 1;
  if (idx < N*KP){
    int n = idx / KP, kp = idx - n*KP;
    dst[(size_t)kp*N + n] = pkh2(src[(size_t)n*K + 2*kp], src[(size_t)n*K + 2*kp + 1]);
  }
}

// ---------- prep: encoder Whh -> f16 12-row layout [dir][i 48][t 512] uint4 ----------
// t=(rg=t>>3, cg=t&7); i=(k=i>>2, q=i&3). value = row rg*12+k, cols cg*32+q*8..+8
__global__ __launch_bounds__(256) void k_prep_wenc(const float* __restrict__ WF,
                                                   const float* __restrict__ WB,
                                                   uint4* __restrict__ dst){
  int idx = blockIdx.x*256 + threadIdx.x;   // 49152 = 2*48*512
  int dir = idx / 24576, rem = idx - dir*24576;
  int i = rem >> 9, t = rem & 511;
  int rg = t >> 3, cg = t & 7;
  int k = i >> 2, q = i & 3;
  const float* s = (dir ? WB : WF) + (size_t)(rg*12 + k)*HE + cg*32 + q*8;
  uint4 v; v.x=pkh2(s[0],s[1]); v.y=pkh2(s[2],s[3]); v.z=pkh2(s[4],s[5]); v.w=pkh2(s[6],s[7]);
  dst[idx] = v;
}

// ---------- prep: decoder Whh -> f16 M-parallel layout ----------
__global__ __launch_bounds__(256) void k_prep_wdec(const float* __restrict__ src,
                                                   uint4* __restrict__ dst){
  int idx = blockIdx.x*256 + threadIdx.x;   // 98304 = 64*24*64
  int lane = idx & 63;
  int ci = lane & 7, kq = lane >> 3;
  int rest = idx >> 6;                      // cg*24 + g*8 + u
  int u = rest & 7, g = (rest >> 3) % 3, cg = rest / 24;
  int row = g*512 + cg*8 + ci;
  int col = kq*64 + u*8;
  const float* s = src + (size_t)row*HD + col;
  uint4 v; v.x=pkh2(s[0],s[1]); v.y=pkh2(s[2],s[3]); v.z=pkh2(s[4],s[5]); v.w=pkh2(s[6],s[7]);
  dst[idx] = v;
}

// ---------- prep: gi[v][g] = emb[v]@dWih[g] + bih[g] ----------
__global__ __launch_bounds__(256) void k_gi_tab(const float* __restrict__ emb,
                                                const float* __restrict__ Wih,
                                                const float* __restrict__ bih,
                                                float* __restrict__ gi){
  int v = blockIdx.x, gy = blockIdx.y;   // grid (30, 6)
  int g = gy*256 + threadIdx.x;
  __shared__ float e_s[EMBD];
  if (threadIdx.x < EMBD) e_s[threadIdx.x] = emb[(size_t)v*EMBD + threadIdx.x];
  __syncthreads();
  const float4* w4 = (const float4*)(Wih + (size_t)g*EMBD);
  float acc = 0.f;
  #pragma unroll 8
  for (int k = 0; k < EMBD/4; ++k){
    float4 w = w4[k];
    float4 h = *(const float4*)&e_s[k*4];
    acc = fmaf(w.x,h.x,fmaf(w.y,h.y,fmaf(w.z,h.z,fmaf(w.w,h.w,acc))));
  }
  gi[(size_t)v*G3D + g] = acc + bih[g];
}

// ---------- prep: h0 f32 -> f16 ----------
__global__ __launch_bounds__(256) void k_h0cvt(const float* __restrict__ src,
                                               f16* __restrict__ dst){
  int i = blockIdx.x*256 + threadIdx.x;   // 65536
  dst[i] = (f16)src[i];
}

// ---------- encoder: one block per (batch, direction), 512 threads ----------
// 8 waves = 2/SIMD -> 256 arch-VGPR budget; thread holds 12 rows x 32 cols of
// Whh (192 u32) in TRUE VGPRs (no AGPR accvgpr_read per use — the round<=12
// structural cost at 768 threads). Partials via padded LDS p[768][9]
// (writes 2-way=free, reads 9-coprime-32 conflict-free); 256-thread gates.
__global__ __launch_bounds__(512, 2) void k_enc_p(
    const float* __restrict__ x,
    const uint4* __restrict__ Wp,               // [2][48][512] uint4
    const float* __restrict__ WihF, const float* __restrict__ WihB,
    const float* __restrict__ bihF, const float* __restrict__ bhhF,
    const float* __restrict__ bihB, const float* __restrict__ bhhB,
    u16* __restrict__ enc_out, float* __restrict__ h0out)
{
  const int b   = blockIdx.x >> 1;
  const int dir = blockIdx.x & 1;
  const int tid = threadIdx.x;
  const int cg  = tid & 7;
  const float* Wih = dir ? WihB : WihF;
  const float* bih = dir ? bihB : bihF;
  const float* bhh = dir ? bhhB : bhhF;

  __shared__ __align__(16) f16 h_pad[8*40];   // 640 B
  __shared__ float p_lds[G3E*9];              // 27.6 KB padded partials

  // weight tile -> 48 uint4 (192 VGPRs), coalesced
  uint4 w4[48];
  {
    const uint4* wsrc = Wp + (size_t)dir*24576 + tid;
    #pragma unroll
    for (int i = 0; i < 48; ++i) w4[i] = wsrc[(size_t)i*512];
  }
  // gates-thread constants (tid<256): Wih/bias for rows j, j+256, j+512
  float wv0r=0.f,wv1r=0.f,wv0z=0.f,wv1z=0.f,wv0n=0.f,wv1n=0.f;
  float br=0.f,bz=0.f,bin=0.f,bhn=0.f;
  float h_own = 0.f;
  if (tid < HE){
    const int j = tid;
    wv0r = Wih[j*2];         wv1r = Wih[j*2+1];
    wv0z = Wih[(j+HE)*2];    wv1z = Wih[(j+HE)*2+1];
    wv0n = Wih[(j+2*HE)*2];  wv1n = Wih[(j+2*HE)*2+1];
    br  = bih[j] + bhh[j];
    bz  = bih[j+HE] + bhh[j+HE];
    bin = bih[j+2*HE];
    bhn = bhh[j+2*HE];
    h_pad[(j >> 5)*40 + (j & 31)] = (f16)0.f;
  }
  const int rowbase = (tid >> 3)*12;          // rg*12
  __syncthreads();

  for (int t = 0; t < TT; ++t){
    const int tt = dir ? (TT-1-t) : t;
    const float x0 = x[((size_t)b*TT + tt)*2 + 0];
    const float x1 = x[((size_t)b*TT + tt)*2 + 1];

    // dot: 12 rows x 32-col slice (4 b128 broadcast-group reads)
    {
      const uint4* hv = (const uint4*)(h_pad + cg*40);
      uint4 h0 = hv[0], h1 = hv[1], h2 = hv[2], h3 = hv[3];
      #pragma unroll
      for (int k = 0; k < 12; ++k){
        float a = 0.f;
        dot_u4(w4[k*4+0], h0, a);
        dot_u4(w4[k*4+1], h1, a);
        dot_u4(w4[k*4+2], h2, a);
        dot_u4(w4[k*4+3], h3, a);
        p_lds[(rowbase + k)*9 + cg] = a;
      }
    }
    __syncthreads();
    if (tid < HE){
      const int j = tid;
      float sr=0.f, sz=0.f, sn=0.f;
      #pragma unroll
      for (int k = 0; k < 8; ++k){
        sr += p_lds[j*9 + k];
        sz += p_lds[(j+HE)*9 + k];
        sn += p_lds[(j+2*HE)*9 + k];
      }
      float gr = sr + fmaf(wv0r, x0, wv1r*x1) + br;
      float gz = sz + fmaf(wv0z, x0, wv1z*x1) + bz;
      float gni = fmaf(wv0n, x0, wv1n*x1) + bin;
      float r = sigm(gr), z = sigm(gz);
      float n = ftanh(gni + r*(sn + bhn));
      float hnew = (1.f - z)*n + z*h_own;
      h_own = hnew;
      h_pad[(j >> 5)*40 + (j & 31)] = (f16)hnew;
      enc_out[((size_t)b*TT + tt)*HD + dir*HE + j] = f2h(hnew);
    }
    __syncthreads();
  }
  if (tid < HE) h0out[(size_t)b*HD + dir*HE + tid] = h_own;
}

// ---------- decoder: ONE STEP per launch, M-parallel ----------
__global__ __launch_bounds__(256, 2) void k_dstep(
    const int* __restrict__ tgt, const float* __restrict__ gi_tab,
    const uint4* __restrict__ Wd2, const float* __restrict__ bhh,
    const f16* __restrict__ h_prev, f16* __restrict__ h_next,
    float* __restrict__ Hall, int l)
{
  const int bg = blockIdx.x & 7, cg = blockIdx.x >> 3;
  const int tid = threadIdx.x;
  const int ci = tid & 7, kq = (tid >> 3) & 7, bq = tid >> 6;

  __shared__ __align__(16) f16 h_s[16][8][72];    // 18.4 KB, padded segments
  __shared__ float p_s[3][16][8][9];              // 13.8 KB [g][b][ci][kq+pad]
  __shared__ int tok_s[16];

  uint4 w[24];
  {
    const uint4* wp = Wd2 + (size_t)cg*24*64 + (kq*8 + ci);
    #pragma unroll
    for (int i = 0; i < 24; ++i) w[i] = wp[(size_t)i*64];
  }
  {
    const uint4* hsrc = (const uint4*)(h_prev + (size_t)bg*16*HD);
    #pragma unroll
    for (int i = 0; i < 4; ++i){
      int idx = tid + i*256;
      int b = idx >> 6, w4 = idx & 63;
      int kq2 = w4 >> 3, off = w4 & 7;
      *(uint4*)&h_s[b][kq2][off*8] = hsrc[idx];
    }
  }
  if (tid < 16) tok_s[tid] = (l == 0) ? 1 : tgt[(size_t)(bg*16 + tid)*LL + l - 1];
  __syncthreads();

  #pragma unroll
  for (int nb = 0; nb < 4; ++nb){
    const int b = bq*4 + nb;
    const uint4* hv = (const uint4*)&h_s[b][kq][0];
    float x0 = 0.f, x1 = 0.f, x2 = 0.f;
    #pragma unroll
    for (int u = 0; u < 8; ++u){
      uint4 hh = hv[u];
      dot_u4(w[u],      hh, x0);
      dot_u4(w[8 + u],  hh, x1);
      dot_u4(w[16 + u], hh, x2);
    }
    p_s[0][b][ci][kq] = x0;
    p_s[1][b][ci][kq] = x1;
    p_s[2][b][ci][kq] = x2;
  }
  __syncthreads();

  if (tid < 128){
    const int b = tid >> 3, cl = tid & 7;
    const int C = cg*8 + cl;
    float s0 = 0.f, s1 = 0.f, s2 = 0.f;
    #pragma unroll
    for (int k = 0; k < 8; ++k){
      s0 += p_s[0][b][cl][k];
      s1 += p_s[1][b][cl][k];
      s2 += p_s[2][b][cl][k];
    }
    const int tok = tok_s[b];
    const float* gp = gi_tab + (size_t)tok*G3D + C;
    float r = sigm(gp[0]    + s0 + bhh[C]);
    float z = sigm(gp[HD]   + s1 + bhh[HD + C]);
    float n = ftanh(gp[2*HD] + r*(s2 + bhh[2*HD + C]));
    float hp = (float)h_s[b][C >> 6][C & 63];
    float hnew = (1.f - z)*n + z*hp;
    const int gb = bg*16 + b;
    h_next[(size_t)gb*HD + C] = (f16)hnew;
    Hall[((size_t)l*BB + gb)*HD + C] = hnew;
  }
}

// ---------- Q = Hall @ WqT + bq -> f16 ; grid (128 rt, 8 nt), dot2 inner ----------
__global__ __launch_bounds__(256) void k_query(const float* __restrict__ Hall,
                                               const u32* __restrict__ Wq2,
                                               const float* __restrict__ bq,
                                               u16* __restrict__ Qh){
  const int rt = blockIdx.x, nt = blockIdx.y;
  const int tid = threadIdx.x;
  __shared__ u32 A2_s[16*68];
  __shared__ u32 B2_s[16*68];
  const int rq = tid >> 4, nq = tid & 15;
  const int i = tid >> 2, jj = tid & 3;
  const int i3 = tid >> 4, n4 = tid & 15;
  float acc[16] = {};
  for (int kc = 0; kc < 16; ++kc){
    __syncthreads();
    {
      const float* src = Hall + (size_t)(rt*64 + i)*HD + kc*32 + jj*8;
      float4 v0 = *(const float4*)src, v1 = *(const float4*)(src+4);
      A2_s[(jj*4+0)*68+i] = pkrtz(v0.x, v0.y);
      A2_s[(jj*4+1)*68+i] = pkrtz(v0.z, v0.w);
      A2_s[(jj*4+2)*68+i] = pkrtz(v1.x, v1.y);
      A2_s[(jj*4+3)*68+i] = pkrtz(v1.z, v1.w);
    }
    {
      uint4 v = *(const uint4*)(Wq2 + (size_t)(kc*16 + i3)*HD + nt*64 + n4*4);
      *(uint4*)&B2_s[i3*68 + n4*4] = v;
    }
    __syncthreads();
    INNER8P(rq, nq)
  }
  const int n0 = nt*64 + nq*4;
  float4 bv = *(const float4*)&bq[n0];
  #pragma unroll
  for (int r = 0; r < 4; ++r){
    u16* dst = Qh + (size_t)(rt*64 + rq*4 + r)*HD + n0;
    *(ushort4*)dst = hpk4(acc[r*4+0]+bv.x, acc[r*4+1]+bv.y,
                          acc[r*4+2]+bv.z, acc[r*4+3]+bv.w);
  }
}

// ---------- S[b][l][t] = Q[b,l,:] . enc[b,t,:] ; grid (128 b, 8 tt), dot2 ----------
__global__ __launch_bounds__(256) void k_scores(const u16* __restrict__ Qh,
                                                const u16* __restrict__ enc,
                                                float* __restrict__ Sbuf){
  const int bI = blockIdx.x, tt = blockIdx.y;
  const int tid = threadIdx.x;
  __shared__ u32 A2_s[16*68];
  __shared__ u32 B2_s[16*68];
  const int lq = tid >> 4, tq = tid & 15;
  const int i = tid >> 2, jj = tid & 3;
  float acc[16] = {};
  for (int kc = 0; kc < 16; ++kc){
    __syncthreads();
    {
      uint4 va = *(const uint4*)(Qh + ((size_t)i*BB + bI)*HD + kc*32 + jj*8);
      A2_s[(jj*4+0)*68+i] = va.x;
      A2_s[(jj*4+1)*68+i] = va.y;
      A2_s[(jj*4+2)*68+i] = va.z;
      A2_s[(jj*4+3)*68+i] = va.w;
    }
    {
      uint4 vb = *(const uint4*)(enc + ((size_t)bI*TT + tt*64 + i)*HD + kc*32 + jj*8);
      B2_s[(jj*4+0)*68+i] = vb.x;
      B2_s[(jj*4+1)*68+i] = vb.y;
      B2_s[(jj*4+2)*68+i] = vb.z;
      B2_s[(jj*4+3)*68+i] = vb.w;
    }
    __syncthreads();
    INNER8P(lq, tq)
  }
  #pragma unroll
  for (int r = 0; r < 4; ++r){
    float4 o = make_float4(acc[r*4+0],acc[r*4+1],acc[r*4+2],acc[r*4+3]);
    *(float4*)&Sbuf[((size_t)bI*LL + lq*4+r)*TT + tt*64 + tq*4] = o;
  }
}

// ---------- row softmax over t: P f16 ; grid 8192 x 64 ----------
__global__ __launch_bounds__(64) void k_softmax(const float* __restrict__ Sbuf,
                                                u16* __restrict__ Ph){
  const int row = blockIdx.x;
  const int lane = threadIdx.x;
  const float* s = Sbuf + (size_t)row*TT;
  float v[8]; float m = -1e30f;
  #pragma unroll
  for (int i = 0; i < 8; ++i){ v[i] = s[lane + i*64]; m = fmaxf(m, v[i]); }
  #pragma unroll
  for (int o = 32; o; o >>= 1) m = fmaxf(m, __shfl_xor(m, o));
  float Z = 0.f;
  #pragma unroll
  for (int i = 0; i < 8; ++i){ v[i] = fexp2(1.4426950408889634f*(v[i] - m)); Z += v[i]; }
  #pragma unroll
  for (int o = 32; o; o >>= 1) Z += __shfl_xor(Z, o);
  float inv = frcp(Z);
  u16* p = Ph + (size_t)row*TT;
  #pragma unroll
  for (int i = 0; i < 8; ++i) p[lane + i*64] = f2h(v[i]*inv);
}

// ---------- attn[b][t][l] = f32(P[b][l][t]) ; grid (128 b, 8 tt) ----------
__global__ __launch_bounds__(256) void k_attn_tr(const u16* __restrict__ Ph,
                                                 float* __restrict__ att){
  const int bI = blockIdx.x, tt = blockIdx.y;
  const int tid = threadIdx.x;
  __shared__ u16 tile[64][72];
  {
    const int i = tid >> 2, jj = tid & 3;
    #pragma unroll
    for (int rep = 0; rep < 2; ++rep){
      int ch = jj + rep*4;
      uint4 v = *(const uint4*)(Ph + ((size_t)bI*LL + i)*TT + tt*64 + ch*8);
      *(uint4*)&tile[i][ch*8] = v;
    }
  }
  __syncthreads();
  const int t = tid >> 2, jl = tid & 3;
  #pragma unroll
  for (int rep = 0; rep < 4; ++rep){
    int l0 = jl*16 + rep*4;
    float4 o;
    o.x = h2f(tile[l0+0][t]); o.y = h2f(tile[l0+1][t]);
    o.z = h2f(tile[l0+2][t]); o.w = h2f(tile[l0+3][t]);
    *(float4*)&att[((size_t)bI*TT + tt*64 + t)*LL + l0] = o;
  }
}

// ---------- ctx[l*128+b][n] = P[b,l,:] @ enc[b,:,n] -> f16 ; dot2 inner ----------
__global__ __launch_bounds__(256) void k_ctx(const u16* __restrict__ Ph,
                                             const u16* __restrict__ enc,
                                             u16* __restrict__ ctxh){
  const int bI = blockIdx.x, nt = blockIdx.y;
  const int tid = threadIdx.x;
  __shared__ u32 A2_s[16*68];
  __shared__ u32 B2_s[16*68];
  const int lq = tid >> 4, nq = tid & 15;
  const int i = tid >> 2, jj = tid & 3;
  const int q = tid >> 4, n4 = tid & 15;
  float acc[16] = {};
  for (int tc = 0; tc < 16; ++tc){
    __syncthreads();
    {
      uint4 va = *(const uint4*)(Ph + ((size_t)bI*LL + i)*TT + tc*32 + jj*8);
      A2_s[(jj*4+0)*68+i] = va.x;
      A2_s[(jj*4+1)*68+i] = va.y;
      A2_s[(jj*4+2)*68+i] = va.z;
      A2_s[(jj*4+3)*68+i] = va.w;
    }
    {
      const int t0 = tc*32 + 2*q;
      const int n0 = nt*64 + n4*4;
      uint2 a = *(const uint2*)(enc + ((size_t)bI*TT + t0)*HD + n0);
      uint2 b = *(const uint2*)(enc + ((size_t)bI*TT + t0 + 1)*HD + n0);
      B2_s[q*68 + n4*4 + 0] = (a.x & 0xffffu) | (b.x << 16);
      B2_s[q*68 + n4*4 + 1] = (a.x >> 16) | (b.x & 0xffff0000u);
      B2_s[q*68 + n4*4 + 2] = (a.y & 0xffffu) | (b.y << 16);
      B2_s[q*68 + n4*4 + 3] = (a.y >> 16) | (b.y & 0xffff0000u);
    }
    __syncthreads();
    INNER8P(lq, nq)
  }
  const int n0 = nt*64 + nq*4;
  #pragma unroll
  for (int r = 0; r < 4; ++r){
    int ll = lq*4 + r;
    u16* dst = ctxh + ((size_t)ll*BB + bI)*HD + n0;
    *(ushort4*)dst = hpk4(acc[r*4+0], acc[r*4+1], acc[r*4+2], acc[r*4+3]);
  }
}

// ---------- o = [Hall|ctx] @ WcT + bc ; grid (128 rt, 4 nt), dot2 ----------
__global__ __launch_bounds__(256) void k_outc(const float* __restrict__ Hall,
                                              const u16* __restrict__ ctxh,
                                              const u32* __restrict__ Wc2,
                                              const float* __restrict__ bc,
                                              float* __restrict__ obuf){
  const int rt = blockIdx.x, nt = blockIdx.y;
  const int tid = threadIdx.x;
  __shared__ u32 A2_s[16*68];
  __shared__ u32 B2_s[16*68];
  const int rq = tid >> 4, nq = tid & 15;
  const int i = tid >> 2, jj = tid & 3;
  const int i3 = tid >> 4, n4 = tid & 15;
  float acc[16] = {};
  for (int kc = 0; kc < 32; ++kc){
    __syncthreads();
    if (kc < 16){
      const float* src = Hall + (size_t)(rt*64 + i)*HD + kc*32 + jj*8;
      float4 v0 = *(const float4*)src, v1 = *(const float4*)(src+4);
      A2_s[(jj*4+0)*68+i] = pkrtz(v0.x, v0.y);
      A2_s[(jj*4+1)*68+i] = pkrtz(v0.z, v0.w);
      A2_s[(jj*4+2)*68+i] = pkrtz(v1.x, v1.y);
      A2_s[(jj*4+3)*68+i] = pkrtz(v1.z, v1.w);
    } else {
      uint4 v = *(const uint4*)(ctxh + (size_t)(rt*64 + i)*HD + (kc-16)*32 + jj*8);
      A2_s[(jj*4+0)*68+i] = v.x;
      A2_s[(jj*4+1)*68+i] = v.y;
      A2_s[(jj*4+2)*68+i] = v.z;
      A2_s[(jj*4+3)*68+i] = v.w;
    }
    {
      uint4 v = *(const uint4*)(Wc2 + (size_t)(kc*16 + i3)*256 + nt*64 + n4*4);
      *(uint4*)&B2_s[i3*68 + n4*4] = v;
    }
    __syncthreads();
    INNER8P(rq, nq)
  }
  const int n0 = nt*64 + nq*4;
  float4 bv = *(const float4*)&bc[n0];
  #pragma unroll
  for (int r = 0; r < 4; ++r){
    float4 o = make_float4(acc[r*4+0]+bv.x, acc[r*4+1]+bv.y,
                           acc[r*4+2]+bv.z, acc[r*4+3]+bv.w);
    *(float4*)&obuf[(size_t)(rt*64 + rq*4 + r)*256 + n0] = o;
  }
}

// ---------- logits = o @ Wf^T + bf ; grid 128 ----------
__global__ __launch_bounds__(256) void k_fc(const float* __restrict__ obuf,
                                            const float* __restrict__ Wf,
                                            const float* __restrict__ bfv,
                                            float* __restrict__ out_vec){
  const int rt = blockIdx.x;
  const int tid = threadIdx.x;
  __shared__ float w_s[30*260];
  for (int rr = 0; rr < 30; ++rr) w_s[rr*260 + tid] = Wf[(size_t)rr*256 + tid];
  __syncthreads();
  const int rl = tid >> 2, dq = tid & 3;
  const int r = rt*64 + rl;
  float acc[8] = {};
  for (int k = 0; k < 256; k += 4){
    float4 o4 = *(const float4*)&obuf[(size_t)r*256 + k];
    #pragma unroll
    for (int jq = 0; jq < 8; ++jq){
      int d = dq*8 + jq;
      if (d < 30){
        float4 w4 = *(const float4*)&w_s[d*260 + k];
        acc[jq] = fmaf(o4.x,w4.x,fmaf(o4.y,w4.y,fmaf(o4.z,w4.z,fmaf(o4.w,w4.w,acc[jq]))));
      }
    }
  }
  const int b = r & 127, l = r >> 7;
  #pragma unroll
  for (int jq = 0; jq < 8; ++jq){
    int d = dq*8 + jq;
    if (d < 30) out_vec[((size_t)b*LL + l)*NDICT + d] = acc[jq] + bfv[d];
  }
}

__global__ __launch_bounds__(256) void k_copy(const float* __restrict__ src,
                                              float* __restrict__ dst, int n){
  int i = blockIdx.x*256 + threadIdx.x;
  if (i < n) dst[i] = src[i];
}

extern "C" void kernel_launch(void* const* d_in, const int* in_sizes, int n_in,
                              void* d_out, int out_size, void* d_ws, size_t ws_size,
                              hipStream_t stream)
{
  const float* x     = (const float*)d_in[0];
  const int*   tgt   = (const int*)  d_in[1];
  const float* eWihF = (const float*)d_in[2];
  const float* eWhhF = (const float*)d_in[3];
  const float* ebihF = (const float*)d_in[4];
  const float* ebhhF = (const float*)d_in[5];
  const float* eWihB = (const float*)d_in[6];
  const float* eWhhB = (const float*)d_in[7];
  const float* ebihB = (const float*)d_in[8];
  const float* ebhhB = (const float*)d_in[9];
  const float* emb   = (const float*)d_in[10];
  const float* dWih  = (const float*)d_in[11];
  const float* dWhh  = (const float*)d_in[12];
  const float* dbih  = (const float*)d_in[13];
  const float* dbhh  = (const float*)d_in[14];
  const float* Wq    = (const float*)d_in[15];
  const float* bq    = (const float*)d_in[16];
  const float* Wc    = (const float*)d_in[17];
  const float* bc    = (const float*)d_in[18];
  const float* Wf    = (const float*)d_in[19];
  const float* bfv   = (const float*)d_in[20];

  char* w = (char*)d_ws;
  uint4* Wpenc = (uint4*)w; w += 786432;     // [2][48][512] uint4 f16 12-row layout
  uint4* Wpdec = (uint4*)w; w += 1572864;    // [64][24][64] uint4 f16 M-parallel
  u32*   Wq2   = (u32*)w;  w += 524288;      // [256 kp][512 n] f16 pairs
  u32*   Wc2   = (u32*)w;  w += 524288;      // [512 kp][256 n] f16 pairs
  float* gi_t  = (float*)w; w += 184320;
  float* h0buf = (float*)w; w += 262144;
  f16*   h16A  = (f16*)w; w += 131072;       // [128][512] f16
  f16*   h16B  = (f16*)w; w += 131072;
  float* Hall  = (float*)w; w += 16777216;
  u16*   Qh    = (u16*)w;                    // aliased: Ph reuses after k_scores
  u16*   Ph    = (u16*)w; w += 8388608;
  float* Sbuf  = (float*)w;                  // aliased over (ctxh | obuf)
  u16*   ctxh  = (u16*)w; w += 8388608;
  float* obuf  = (float*)w; w += 8388608;
  u16*   ench  = (u16*)w; w += 67108864;

  float* out     = (float*)d_out;
  float* out_vec = out;                              // [128][64][30]
  float* out_hT  = out + (size_t)BB*LL*NDICT;        // [1][128][512]
  float* out_att = out_hT + (size_t)BB*HD;           // [128][512][64]

  // prep
  k_prep_wenc<<<192, 256, 0, stream>>>(eWhhF, eWhhB, Wpenc);
  k_prep_wdec<<<384, 256, 0, stream>>>(dWhh, Wpdec);
  k_prep_pairT<<<512, 256, 0, stream>>>(Wq, Wq2, HD, HD);
  k_prep_pairT<<<512, 256, 0, stream>>>(Wc, Wc2, 256, 1024);
  k_gi_tab<<<dim3(NDICT, 6), 256, 0, stream>>>(emb, dWih, dbih, gi_t);

  // encoder: 256 independent recurrences, 512-thread blocks, true-VGPR weights
  k_enc_p<<<BB*2, 512, 0, stream>>>(x, Wpenc, eWihF, eWihB,
                                    ebihF, ebhhF, ebihB, ebhhB, ench, h0buf);

  // decoder recurrence: one launch per step, M-parallel, conflict-free LDS
  k_h0cvt<<<256, 256, 0, stream>>>(h0buf, h16A);
  for (int l = 0; l < LL; ++l){
    const f16* hp = (l & 1) ? h16B : h16A;
    f16*       hn = (l & 1) ? h16A : h16B;
    k_dstep<<<512, 256, 0, stream>>>(tgt, gi_t, Wpdec, dbhh, hp, hn, Hall, l);
  }

  // batched post-recurrence pipeline
  k_query<<<dim3(128,8), 256, 0, stream>>>(Hall, Wq2, bq, Qh);
  k_scores<<<dim3(128,8), 256, 0, stream>>>(Qh, ench, Sbuf);
  k_softmax<<<BB*LL, 64, 0, stream>>>(Sbuf, Ph);
  k_attn_tr<<<dim3(128,8), 256, 0, stream>>>(Ph, out_att);
  k_ctx<<<dim3(128,8), 256, 0, stream>>>(Ph, ench, ctxh);
  k_outc<<<dim3(128,4), 256, 0, stream>>>(Hall, ctxh, Wc2, bc, obuf);
  k_fc<<<BB, 256, 0, stream>>>(obuf, Wf, bfv, out_vec);
  k_copy<<<(BB*HD+255)/256, 256, 0, stream>>>(Hall + (size_t)63*BB*HD, out_hT, BB*HD);
}